// Round 5
// baseline (415.645 us; speedup 1.0000x reference)
//
#include <hip/hip_runtime.h>

// GroupedConv2d via bf16 MFMA implicit GEMM — band pipeline, 2 j-tiles/wave.
// G=8 groups x 32 gathered channels -> J=64, 3x3 pad=1.
// x[16,256,56,56] fp32 -> out[16,512,56,56] fp32.
//
// Block = (g, b, 8-row chunk) -> grid (7,16,8)=896. 4 bands of 2 rows.
// Waves: wid = (jp, th). jp owns j in [jp*32, jp*32+32) as 2 j-tiles (A-frags
// for both in regs, 72 VGPR) -> each B-frag ds_read_b128 feeds 2 MFMAs.
// th splits the 7 pixel tiles 4/3. Pipeline per band: (A) issue next band's
// global loads, (B) MFMA compute + direct stores, (C) convert+write next band
// into other LDS buffer, 1 barrier. LDS pixel stride 80 B (b128-aligned).

#define NG 8
#define CPER 32
#define CIN 256
#define NJ 64
#define NB 16
#define NH 56
#define NW 56
#define HW (NH * NW)
#define PXST 40                  // shorts per LDS pixel (32 ch + 8 pad) = 80 B
#define BUFSH (4 * 58 * PXST)    // 9280 shorts per band buffer
#define NPACK (16 * 4 * 58)      // 3712 channel-pair packs per band
#define NITER 15
#define WEI_SH (9 * 2048)        // weight stage: [tap][j*32+c] bf16

typedef __attribute__((ext_vector_type(8))) short short8v;
typedef __attribute__((ext_vector_type(4))) float float4v;

__device__ __forceinline__ unsigned bf16rne(float f) {
    unsigned u = __float_as_uint(f);
    return (u + 0x7FFFu + ((u >> 16) & 1u)) >> 16;
}

__global__ __launch_bounds__(256, 3)
void gconv_mfma(const float* __restrict__ x,
                const float* __restrict__ w,
                const float* __restrict__ bias,
                const int* __restrict__ arr,
                float* __restrict__ out) {
    __shared__ __align__(16) unsigned short smem[2 * BUFSH];

    const int tid   = threadIdx.x;
    const int chunk = blockIdx.x;      // 0..6 -> rows [chunk*8, chunk*8+8)
    const int b     = blockIdx.y;
    const int g     = blockIdx.z;
    const int lane  = tid & 63;
    const int wid   = tid >> 6;
    const int jp    = wid & 1;         // j-pair: j in [jp*32, jp*32+32)
    const int th    = wid >> 1;        // tile-half: tiles {0..3} / {4..6}
    const int n     = lane & 15;
    const int kq    = lane >> 4;
    const int r0c   = chunk * 8;

    const float* xb = x + (size_t)b * (CIN * HW);

    // ---- staging descriptors (band-invariant) ----
    int pre0[NITER], meta[NITER];
    #pragma unroll
    for (int k = 0; k < NITER; ++k) {
        int e = tid + 256 * k;
        bool act = (k < 14) || (tid < NPACK - 3584);   // last iter partial
        int c2   = e / 232;            // 232 = 4*58
        int rem  = e - c2 * 232;
        int row  = rem / 58;           // LDS row = input row rb-1+row
        int colp = rem - row * 58;     // input col colp-1
        int ch0 = 0, dch = 0;
        if (act) {
            int i0 = arr[g * CPER + 2 * c2];
            int i1 = arr[g * CPER + 2 * c2 + 1];
            ch0 = i0; dch = i1 - i0;
        }
        pre0[k] = ch0 * HW + (row - 1) * NW + (colp - 1);
        int cv = ((unsigned)(colp - 1) < (unsigned)NW) ? 1 : 0;
        meta[k] = ((row * 58 + colp) * PXST + c2 * 2) | (row << 14)
                | (cv << 16) | ((dch & 0x3FF) << 18);
    }

    // ---- issue band-0 x loads (latency hides under weight staging) ----
    float f0[NITER], f1[NITER];
    {
        int roff = r0c * NW;
        #pragma unroll
        for (int k = 0; k < NITER; ++k) {
            int m = meta[k];
            int row = (m >> 14) & 3;
            bool v = (m & (1 << 16)) && ((unsigned)(r0c - 1 + row) < (unsigned)NH);
            if (k == 14 && tid >= NPACK - 3584) v = false;
            int off = pre0[k] + roff;
            int dch = (m << 4) >> 22;          // sign-extended 10-bit
            f0[k] = v ? xb[off] : 0.0f;
            f1[k] = v ? xb[off + dch * HW] : 0.0f;
        }
    }

    // ---- stage weights: global (strided, L2) -> LDS [tap][j*32+c] bf16 ----
    {
        const float* wg = w + (size_t)g * (NJ * CPER * 9);
        #pragma unroll
        for (int it = 0; it < WEI_SH / 256; ++it) {
            int e   = tid + it * 256;
            int tap = e >> 11;
            int jc  = e & 2047;
            smem[tap * 2048 + jc] = (unsigned short)bf16rne(wg[jc * 9 + tap]);
        }
    }
    __syncthreads();

    short8v A0[9], A1[9];
    {
        const unsigned short* wl = smem + (jp * 32 + n) * CPER + kq * 8;
        #pragma unroll
        for (int t = 0; t < 9; ++t) {
            A0[t] = *(const short8v*)(wl + t * 2048);
            A1[t] = *(const short8v*)(wl + t * 2048 + 16 * CPER);
        }
    }
    float4v binit0, binit1;
    #pragma unroll
    for (int i = 0; i < 4; ++i) {
        binit0[i] = bias[g * NJ + jp * 32 + kq * 4 + i];
        binit1[i] = bias[g * NJ + jp * 32 + 16 + kq * 4 + i];
    }
    __syncthreads();   // all A-frag reads done; smem now band buffers

    // ---- write band 0 into buffer 0 ----
    #pragma unroll
    for (int k = 0; k < NITER; ++k) {
        if (k < 14 || tid < NPACK - 3584)
            *(unsigned*)(&smem[meta[k] & 0x3FFF]) =
                bf16rne(f0[k]) | (bf16rne(f1[k]) << 16);
    }
    __syncthreads();

    const int obase = ((b * (NG * NJ) + g * NJ + jp * 32 + kq * 4) * NH + r0c) * NW;

    for (int bd = 0; bd < 4; ++bd) {
        // ---- phase A: issue next band's loads ----
        if (bd < 3) {
            int rb = r0c + (bd + 1) * 2;
            int roff = rb * NW;
            #pragma unroll
            for (int k = 0; k < NITER; ++k) {
                int m = meta[k];
                int row = (m >> 14) & 3;
                bool v = (m & (1 << 16)) && ((unsigned)(rb - 1 + row) < (unsigned)NH);
                if (k == 14 && tid >= NPACK - 3584) v = false;
                int off = pre0[k] + roff;
                int dch = (m << 4) >> 22;
                f0[k] = v ? xb[off] : 0.0f;
                f1[k] = v ? xb[off + dch * HW] : 0.0f;
            }
        }
        // ---- phase B: compute this band from buf[bd&1] ----
        {
            const unsigned short* buf = smem + (bd & 1) * BUFSH;
            const int ob = obase + bd * 2 * NW;
            if (th == 0) {
                // tiles (0,1) and (2,3) as pairs
                #pragma unroll
                for (int t0 = 0; t0 < 4; t0 += 2) {
                    int pA = t0 * 16 + n;  int rlA = pA >= NW; int colA = pA - rlA * NW;
                    int pB = pA + 16;      int rlB = pB >= NW; int colB = pB - rlB * NW;
                    const unsigned short* bpA = buf + (rlA * 58 + colA) * PXST + kq * 8;
                    const unsigned short* bpB = buf + (rlB * 58 + colB) * PXST + kq * 8;
                    float4v a00 = binit0, a01 = binit1, a10 = binit0, a11 = binit1;
                    #pragma unroll
                    for (int kh = 0; kh < 3; ++kh)
                        #pragma unroll
                        for (int kw = 0; kw < 3; ++kw) {
                            const int tap = kh * 3 + kw;
                            short8v vA = *(const short8v*)(bpA + (kh * 58 + kw) * PXST);
                            short8v vB = *(const short8v*)(bpB + (kh * 58 + kw) * PXST);
                            a00 = __builtin_amdgcn_mfma_f32_16x16x32_bf16(A0[tap], vA, a00, 0, 0, 0);
                            a01 = __builtin_amdgcn_mfma_f32_16x16x32_bf16(A1[tap], vA, a01, 0, 0, 0);
                            a10 = __builtin_amdgcn_mfma_f32_16x16x32_bf16(A0[tap], vB, a10, 0, 0, 0);
                            a11 = __builtin_amdgcn_mfma_f32_16x16x32_bf16(A1[tap], vB, a11, 0, 0, 0);
                        }
                    int oA = ob + rlA * NW + colA;
                    int oB = ob + rlB * NW + colB;
                    #pragma unroll
                    for (int i = 0; i < 4; ++i) {
                        out[oA + i * HW]        = a00[i];
                        out[oA + (16 + i) * HW] = a01[i];
                        out[oB + i * HW]        = a10[i];
                        out[oB + (16 + i) * HW] = a11[i];
                    }
                }
            } else {
                // pair (4,5)
                {
                    int pA = 4 * 16 + n;   int rlA = pA >= NW; int colA = pA - rlA * NW;
                    int pB = pA + 16;      int rlB = pB >= NW; int colB = pB - rlB * NW;
                    const unsigned short* bpA = buf + (rlA * 58 + colA) * PXST + kq * 8;
                    const unsigned short* bpB = buf + (rlB * 58 + colB) * PXST + kq * 8;
                    float4v a00 = binit0, a01 = binit1, a10 = binit0, a11 = binit1;
                    #pragma unroll
                    for (int kh = 0; kh < 3; ++kh)
                        #pragma unroll
                        for (int kw = 0; kw < 3; ++kw) {
                            const int tap = kh * 3 + kw;
                            short8v vA = *(const short8v*)(bpA + (kh * 58 + kw) * PXST);
                            short8v vB = *(const short8v*)(bpB + (kh * 58 + kw) * PXST);
                            a00 = __builtin_amdgcn_mfma_f32_16x16x32_bf16(A0[tap], vA, a00, 0, 0, 0);
                            a01 = __builtin_amdgcn_mfma_f32_16x16x32_bf16(A1[tap], vA, a01, 0, 0, 0);
                            a10 = __builtin_amdgcn_mfma_f32_16x16x32_bf16(A0[tap], vB, a10, 0, 0, 0);
                            a11 = __builtin_amdgcn_mfma_f32_16x16x32_bf16(A1[tap], vB, a11, 0, 0, 0);
                        }
                    int oA = ob + rlA * NW + colA;
                    int oB = ob + rlB * NW + colB;
                    #pragma unroll
                    for (int i = 0; i < 4; ++i) {
                        out[oA + i * HW]        = a00[i];
                        out[oA + (16 + i) * HW] = a01[i];
                        out[oB + i * HW]        = a10[i];
                        out[oB + (16 + i) * HW] = a11[i];
                    }
                }
                // single tile 6
                {
                    int pA = 6 * 16 + n;   int rlA = pA >= NW; int colA = pA - rlA * NW;
                    const unsigned short* bpA = buf + (rlA * 58 + colA) * PXST + kq * 8;
                    float4v a00 = binit0, a01 = binit1;
                    #pragma unroll
                    for (int kh = 0; kh < 3; ++kh)
                        #pragma unroll
                        for (int kw = 0; kw < 3; ++kw) {
                            const int tap = kh * 3 + kw;
                            short8v vA = *(const short8v*)(bpA + (kh * 58 + kw) * PXST);
                            a00 = __builtin_amdgcn_mfma_f32_16x16x32_bf16(A0[tap], vA, a00, 0, 0, 0);
                            a01 = __builtin_amdgcn_mfma_f32_16x16x32_bf16(A1[tap], vA, a01, 0, 0, 0);
                        }
                    int oA = ob + rlA * NW + colA;
                    #pragma unroll
                    for (int i = 0; i < 4; ++i) {
                        out[oA + i * HW]        = a00[i];
                        out[oA + (16 + i) * HW] = a01[i];
                    }
                }
            }
        }
        // ---- phase C: convert + write next band into other buffer ----
        if (bd < 3) {
            unsigned short* dst = smem + ((bd + 1) & 1) * BUFSH;
            #pragma unroll
            for (int k = 0; k < NITER; ++k) {
                if (k < 14 || tid < NPACK - 3584)
                    *(unsigned*)(&dst[meta[k] & 0x3FFF]) =
                        bf16rne(f0[k]) | (bf16rne(f1[k]) << 16);
            }
            __syncthreads();
        }
    }
}

extern "C" void kernel_launch(void* const* d_in, const int* in_sizes, int n_in,
                              void* d_out, int out_size, void* d_ws, size_t ws_size,
                              hipStream_t stream) {
    const float* x    = (const float*)d_in[0];
    const float* wght = (const float*)d_in[1];
    const float* bias = (const float*)d_in[2];
    const int*   arr  = (const int*)d_in[3];
    float* out = (float*)d_out;

    dim3 grid(7, NB, NG);   // 8-row chunks x batch x group = 896 blocks
    gconv_mfma<<<grid, 256, 0, stream>>>(x, wght, bias, arr, out);
}